// Round 14
// baseline (138.770 us; speedup 1.0000x reference)
//
#include <hip/hip_runtime.h>
#include <math.h>

#define BB 4
#define NN 512
#define PP 2048
#define EE 32768
#define FH 128
#define DRBF 32
#define CUT 4.0f
#define PI_F 3.14159265358979323846f
#define NE 4
#define GRID 512
#define CHUNK 256         // raw edges per block (512 x 256 = B*E exactly)
#define RECMAX 8192

struct __align__(16) Rec { float dx, dy, dz; unsigned ap; };

// ws layout: bar@0, gcnt@8 (memset 16B each replay) | recs@256 (128KB) |
//            O@1MB: [2048 atoms][512] floats = 4.2MB
//   O[a][  0..127]=M0  O[a][128..255]=M1  O[a][256..383]=M2   (V[a]@W1_q)
//   O[a][384..511]=C = n_e[a]@W1_n + S[a]@W1_s

__global__ __launch_bounds__(256, 2) void mega_kernel(
    const int* __restrict__ pe, const float* __restrict__ pdisp,
    const float* __restrict__ cell, const float* __restrict__ atom_xyz,
    const float* __restrict__ probe_xyz,
    const float* __restrict__ S, const float* __restrict__ V,
    const float* __restrict__ W1, const float* __restrict__ b1,
    const float* __restrict__ W2, const float* __restrict__ b2,
    const float* __restrict__ W3, const float* __restrict__ b3,
    unsigned* __restrict__ bar, unsigned* __restrict__ gcnt,
    Rec* __restrict__ recs, float* __restrict__ O,
    float* __restrict__ out) {
  __shared__ float inS[4][4][128];   // [atom][V0,V1,V2,S] = 8 KB
  __shared__ float neS[4][128];      // 2 KB
  __shared__ float epS[NE][DRBF];
  __shared__ float h2S[NE][FH];
  __shared__ float part2[4][NE][64];
  __shared__ float rS[NE][3];
  __shared__ unsigned aS[NE];
  __shared__ float cwS[NE];
  __shared__ unsigned pS[NE];

  const int t    = threadIdx.x;
  const int bid  = blockIdx.x;
  const int lane = t & 63;
  const int wave = t >> 6;

  if (bid < 8)
    ((float4*)out)[bid * 256 + t] = make_float4(0.f, 0.f, 0.f, 0.f);

  // =============== Phase F: filter 256 edges (1/thread) -> global queue ===============
  {
    const int e = bid * CHUNK + t;
    const int b = e >> 15;
    const float* cb = cell + b * 9;
    int2 ap = ((const int2*)pe)[e];
    float pd0 = pdisp[e*3], pd1 = pdisp[e*3+1], pd2 = pdisp[e*3+2];
    float d0 = pd0*cb[0] + pd1*cb[3] + pd2*cb[6];
    float d1 = pd0*cb[1] + pd1*cb[4] + pd2*cb[7];
    float d2 = pd0*cb[2] + pd1*cb[5] + pd2*cb[8];
    int ag = b*NN + ap.x;
    int pg = b*PP + ap.y;
    float dx = probe_xyz[pg*3]   - (atom_xyz[ag*3]   + d0);
    float dy = probe_xyz[pg*3+1] - (atom_xyz[ag*3+1] + d1);
    float dz = probe_xyz[pg*3+2] - (atom_xyz[ag*3+2] + d2);
    float dist2 = dx*dx + dy*dy + dz*dz;
    if (dist2 < CUT*CUT) {
      unsigned i = atomicAdd(gcnt, 1u);            // device-scope
      if (i < RECMAX) {
        Rec r; r.dx = dx; r.dy = dy; r.dz = dz;
        r.ap = ((unsigned)ag << 16) | (unsigned)pg;
        recs[i] = r;
      }
    }
  }

  // =============== Phase A: precompute O for 4 atoms ===============
  {
    const int a0 = bid * 4;
    #pragma unroll
    for (int i = 0; i < 2; ++i) {                  // stage V(3x128)+S(128) x4 atoms
      int idx = t + i * 256;
      int a = idx >> 7, w = idx & 127;
      float4 v;
      if (w < 96) v = *(const float4*)&V[(size_t)(a0 + a) * 384 + w * 4];
      else        v = *(const float4*)&S[(size_t)(a0 + a) * 128 + (w - 96) * 4];
      int sec = (w < 96) ? (w >> 5) : 3;
      int k4  = (w < 96) ? (w & 31) : (w - 96);
      *(float4*)&inS[a][sec][k4 * 4] = v;
    }
    __syncthreads();
    #pragma unroll
    for (int i = 0; i < 2; ++i) {
      int idx = t + i * 256;
      int a = idx >> 7, f = idx & 127;
      float v0 = inS[a][0][f], v1 = inS[a][1][f], v2 = inS[a][2][f];
      neS[a][f] = sqrtf(v0*v0 + v1*v1 + v2*v2);
    }
    __syncthreads();

    const int f1 = t & 127;
    const int ah = t >> 7;          // atoms ah*2, ah*2+1
    const int aa = ah * 2, ab = ah * 2 + 1;
    float m00=0.f,m01=0.f,m02=0.f, m10=0.f,m11=0.f,m12=0.f, c0=0.f, c1=0.f;
    {
      const float* Wq = W1 + 32 * FH + f1;     // one load feeds 6 FMAs
      #pragma unroll 4
      for (int k = 0; k < 128; ++k) {
        float w = Wq[k * FH];
        m00 = fmaf(inS[aa][0][k], w, m00); m10 = fmaf(inS[ab][0][k], w, m10);
        m01 = fmaf(inS[aa][1][k], w, m01); m11 = fmaf(inS[ab][1][k], w, m11);
        m02 = fmaf(inS[aa][2][k], w, m02); m12 = fmaf(inS[ab][2][k], w, m12);
      }
      const float* Wn = W1 + 160 * FH + f1;
      #pragma unroll 4
      for (int k = 0; k < 128; ++k) {
        float w = Wn[k * FH];
        c0 = fmaf(neS[aa][k], w, c0); c1 = fmaf(neS[ab][k], w, c1);
      }
      const float* Ws = W1 + 288 * FH + f1;
      #pragma unroll 4
      for (int k = 0; k < 128; ++k) {
        float w = Ws[k * FH];
        c0 = fmaf(inS[aa][3][k], w, c0); c1 = fmaf(inS[ab][3][k], w, c1);
      }
    }
    float* Oa = O + (size_t)(a0 + aa) * 512 + f1;
    Oa[0] = m00; Oa[128] = m01; Oa[256] = m02; Oa[384] = c0;
    float* Ob = O + (size_t)(a0 + ab) * 512 + f1;
    Ob[0] = m10; Ob[128] = m11; Ob[256] = m12; Ob[384] = c1;
  }

  // =============== software grid barrier (all 512 blocks co-resident) ===============
  __syncthreads();
  if (t == 0) {
    __threadfence();   // device-scope release: O, recs, gcnt, out-zero
    __hip_atomic_fetch_add(bar, 1u, __ATOMIC_ACQ_REL, __HIP_MEMORY_SCOPE_AGENT);
    while (__hip_atomic_load(bar, __ATOMIC_ACQUIRE, __HIP_MEMORY_SCOPE_AGENT) < (unsigned)GRID)
      __builtin_amdgcn_s_sleep(2);
  }
  __syncthreads();

  int n = (int)__hip_atomic_load(gcnt, __ATOMIC_ACQUIRE, __HIP_MEMORY_SCOPE_AGENT);
  if (n > RECMAX) n = RECMAX;
  if (n == 0) return;

  const int f1 = t & 127;
  const int eh = t >> 7;
  const float b1v = b1[f1];
  const float b2v = b2[lane];
  const float w3v = W3[lane];
  const float b3v = b3[0];

  // =============== Phase B: MLP over global survivor queue, balanced ===============
  for (int bt = bid; bt * NE < n; bt += GRID) {
    {
      const int s = bt * NE + wave;
      Rec r;
      if (s < n) r = recs[s];
      else { r.dx = 1.f; r.dy = 0.f; r.dz = 0.f; r.ap = 0xFFFFFFFFu; }
      float d = sqrtf(r.dx*r.dx + r.dy*r.dy + r.dz*r.dz);
      float inv = 1.0f / (d + 1e-8f);
      if (lane < DRBF) epS[wave][lane] = sinf(d * (float)(lane+1) * (PI_F/CUT)) / d;
      if (lane == 0) {
        rS[wave][0] = r.dx*inv; rS[wave][1] = r.dy*inv; rS[wave][2] = r.dz*inv;
        aS[wave] = (r.ap == 0xFFFFFFFFu) ? 0u : (r.ap >> 16);
        cwS[wave] = 0.5f * (cosf((PI_F/CUT) * d) + 1.0f);
        pS[wave]  = (r.ap == 0xFFFFFFFFu) ? 0xFFFFFFFFu : (r.ap & 0xFFFFu);
      }
    }
    __syncthreads();

    // L1: thread (f1, eh) -> z for edges eh*2, eh*2+1
    {
      const int e0 = eh*2, e1 = eh*2 + 1;
      const float* Oa  = O + (size_t)aS[e0] * 512 + f1;
      const float* Obp = O + (size_t)aS[e1] * 512 + f1;
      float o00 = Oa[0],  o01 = Oa[128],  o02 = Oa[256],  oc0 = Oa[384];
      float o10 = Obp[0], o11 = Obp[128], o12 = Obp[256], oc1 = Obp[384];
      float z0 = b1v + oc0 + rS[e0][0]*o00 + rS[e0][1]*o01 + rS[e0][2]*o02;
      float z1 = b1v + oc1 + rS[e1][0]*o10 + rS[e1][1]*o11 + rS[e1][2]*o12;
      const float* Wb = W1 + f1;          // RBF rows 0..31
      #pragma unroll
      for (int k = 0; k < DRBF; ++k) {
        float w = Wb[k * FH];
        z0 = fmaf(epS[e0][k], w, z0);
        z1 = fmaf(epS[e1][k], w, z1);
      }
      h2S[e0][f1] = z0 / (1.0f + __expf(-z0));
      h2S[e1][f1] = z1 / (1.0f + __expf(-z1));
    }
    __syncthreads();

    // L2 (k-split): wave = k-quarter, lane = out-feature
    {
      float a0 = 0.f, a1 = 0.f, a2 = 0.f, a3 = 0.f;
      const float* Wq = W2 + (wave * 32) * 64 + lane;
      const float* h0p = &h2S[0][wave * 32];
      const float* h1p = &h2S[1][wave * 32];
      const float* h2p = &h2S[2][wave * 32];
      const float* h3p = &h2S[3][wave * 32];
      #pragma unroll
      for (int k4 = 0; k4 < 8; ++k4) {
        float w0 = Wq[(k4*4 + 0) * 64];
        float w1 = Wq[(k4*4 + 1) * 64];
        float w2 = Wq[(k4*4 + 2) * 64];
        float w3 = Wq[(k4*4 + 3) * 64];
        float4 h0 = *(const float4*)&h0p[k4*4];
        float4 h1 = *(const float4*)&h1p[k4*4];
        float4 h2 = *(const float4*)&h2p[k4*4];
        float4 h3 = *(const float4*)&h3p[k4*4];
        a0 = fmaf(h0.x, w0, a0); a1 = fmaf(h1.x, w0, a1);
        a2 = fmaf(h2.x, w0, a2); a3 = fmaf(h3.x, w0, a3);
        a0 = fmaf(h0.y, w1, a0); a1 = fmaf(h1.y, w1, a1);
        a2 = fmaf(h2.y, w1, a2); a3 = fmaf(h3.y, w1, a3);
        a0 = fmaf(h0.z, w2, a0); a1 = fmaf(h1.z, w2, a1);
        a2 = fmaf(h2.z, w2, a2); a3 = fmaf(h3.z, w2, a3);
        a0 = fmaf(h0.w, w3, a0); a1 = fmaf(h1.w, w3, a1);
        a2 = fmaf(h2.w, w3, a2); a3 = fmaf(h3.w, w3, a3);
      }
      part2[wave][0][lane] = a0;
      part2[wave][1][lane] = a1;
      part2[wave][2][lane] = a2;
      part2[wave][3][lane] = a3;
    }
    __syncthreads();

    // finish: wave = edge, lane = out-feature; silu + W3-dot + scatter
    {
      float z = part2[0][wave][lane] + part2[1][wave][lane]
              + part2[2][wave][lane] + part2[3][wave][lane] + b2v;
      float h2 = z / (1.0f + __expf(-z));
      float rs = h2 * w3v;
      #pragma unroll
      for (int off = 32; off; off >>= 1) rs += __shfl_xor(rs, off, 64);
      if (lane == 0) {
        unsigned p = pS[wave];
        if (p != 0xFFFFFFFFu) atomicAdd(&out[p], (rs + b3v) * cwS[wave]);
      }
    }
    __syncthreads();
  }
}

extern "C" void kernel_launch(void* const* d_in, const int* in_sizes, int n_in,
                              void* d_out, int out_size, void* d_ws, size_t ws_size,
                              hipStream_t stream) {
  const float* S         = (const float*)d_in[0];
  const float* V         = (const float*)d_in[1];
  const float* atom_xyz  = (const float*)d_in[2];
  const float* probe_xyz = (const float*)d_in[3];
  const float* cell      = (const float*)d_in[4];
  const float* pdisp     = (const float*)d_in[5];
  const float* W1        = (const float*)d_in[6];
  const float* b1        = (const float*)d_in[7];
  const float* W2        = (const float*)d_in[8];
  const float* b2        = (const float*)d_in[9];
  const float* W3        = (const float*)d_in[10];
  const float* b3        = (const float*)d_in[11];
  const int*   pe        = (const int*)d_in[12];
  float* out = (float*)d_out;

  unsigned* bar  = (unsigned*)d_ws;                       // [0]
  unsigned* gcnt = (unsigned*)((char*)d_ws + 8);          // [8]
  Rec*      recs = (Rec*)((char*)d_ws + 256);
  float*    O    = (float*)((char*)d_ws + (1u << 20));    // 2048 x 512 floats

  hipMemsetAsync(d_ws, 0, 16, stream);
  mega_kernel<<<GRID, 256, 0, stream>>>(pe, pdisp, cell, atom_xyz, probe_xyz,
                                        S, V, W1, b1, W2, b2, W3, b3,
                                        bar, gcnt, recs, O, out);
}

// Round 15
// 33.454 us; speedup vs baseline: 4.1481x; 4.1481x over previous
//
#include <hip/hip_runtime.h>
#include <math.h>

#define BB 4
#define NN 512
#define PP 2048
#define EE 32768
#define FH 128
#define DRBF 32
#define CUT 4.0f
#define PI_F 3.14159265358979323846f
#define NE 4
#define AT2 8             // atoms per block (atom part)
#define ABLK 1280         // atom blocks: (BB*NN/AT2)*5
#define FBLK 512          // filter blocks: BB*EE/256
#define RECMAX 8192

struct __align__(16) Rec { float dx, dy, dz; unsigned ap; };

// ws: gcnt@0 (memset 16B each replay) | recs@256 (128KB) | O@1MB:
//   O[a][640]: [0..127]=M0 [128..255]=M1 [256..383]=M2 = V[a]@W1_q (rows 32..159)
//              [384..511]=Cn = n_e@W1_n (160..287)  [512..639]=Cs = S@W1_s (288..415)

// Node 2: atom precompute (bid<1280, R12-proven) in parallel with edge filter
// (bid>=1280) pushing survivors to a global compacted queue. Blocks 0-7 zero out.
__global__ __launch_bounds__(256) void combined_kernel(
    const int* __restrict__ pe, const float* __restrict__ pdisp,
    const float* __restrict__ cell, const float* __restrict__ atom_xyz,
    const float* __restrict__ probe_xyz,
    const float* __restrict__ S, const float* __restrict__ V,
    const float* __restrict__ W1,
    unsigned* __restrict__ gcnt, Rec* __restrict__ recs,
    float* __restrict__ O, float* __restrict__ out) {
  __shared__ float inS[AT2][128];   // 4 KB
  const int t   = threadIdx.x;
  const int bid = blockIdx.x;

  if (bid >= ABLK) {
    // ---------------- filter part ----------------
    const int fb = bid - ABLK;
    const int e  = fb * 256 + t;
    const int b  = e >> 15;
    const float* cb = cell + b * 9;
    int2 ap = ((const int2*)pe)[e];
    float pd0 = pdisp[e*3], pd1 = pdisp[e*3+1], pd2 = pdisp[e*3+2];
    float d0 = pd0*cb[0] + pd1*cb[3] + pd2*cb[6];
    float d1 = pd0*cb[1] + pd1*cb[4] + pd2*cb[7];
    float d2 = pd0*cb[2] + pd1*cb[5] + pd2*cb[8];
    int ag = b*NN + ap.x;
    int pg = b*PP + ap.y;
    float dx = probe_xyz[pg*3]   - (atom_xyz[ag*3]   + d0);
    float dy = probe_xyz[pg*3+1] - (atom_xyz[ag*3+1] + d1);
    float dz = probe_xyz[pg*3+2] - (atom_xyz[ag*3+2] + d2);
    float dist2 = dx*dx + dy*dy + dz*dz;
    if (dist2 < CUT*CUT) {
      unsigned i = atomicAdd(gcnt, 1u);          // device-scope
      if (i < RECMAX) {
        Rec r; r.dx = dx; r.dy = dy; r.dz = dz;
        r.ap = ((unsigned)ag << 16) | (unsigned)pg;
        recs[i] = r;
      }
    }
    return;
  }

  // ---------------- atom part (R12-proven) ----------------
  if (bid < 8)
    ((float4*)out)[bid * 256 + t] = make_float4(0.f, 0.f, 0.f, 0.f);

  const int fam = bid % 5;
  const int a0  = (bid / 5) * AT2;

  {
    int a  = t >> 5;          // 0..7
    int k4 = t & 31;          // float4 index 0..31
    float4 v;
    if (fam < 3) {
      v = *(const float4*)&V[(size_t)(a0 + a) * 384 + fam * 128 + k4 * 4];
    } else if (fam == 4) {
      v = *(const float4*)&S[(size_t)(a0 + a) * 128 + k4 * 4];
    } else { // fam == 3: n_e from V
      float4 x = *(const float4*)&V[(size_t)(a0 + a) * 384 +   0 + k4 * 4];
      float4 y = *(const float4*)&V[(size_t)(a0 + a) * 384 + 128 + k4 * 4];
      float4 z = *(const float4*)&V[(size_t)(a0 + a) * 384 + 256 + k4 * 4];
      v.x = sqrtf(x.x*x.x + y.x*y.x + z.x*z.x);
      v.y = sqrtf(x.y*x.y + y.y*y.y + z.y*z.y);
      v.z = sqrtf(x.z*x.z + y.z*y.z + z.z*z.z);
      v.w = sqrtf(x.w*x.w + y.w*y.w + z.w*z.w);
    }
    *(float4*)&inS[a][k4 * 4] = v;
  }
  __syncthreads();

  const int f1 = t & 127;
  const int ah = t >> 7;     // atoms ah*4 .. ah*4+3
  const int wrow = (fam < 3) ? 32 : ((fam == 3) ? 160 : 288);
  const float* Wb = W1 + (size_t)wrow * FH + f1;

  float acc0 = 0.f, acc1 = 0.f, acc2 = 0.f, acc3 = 0.f;
  #pragma unroll 4
  for (int k4 = 0; k4 < 32; ++k4) {
    float w0 = Wb[(k4*4 + 0) * FH];
    float w1 = Wb[(k4*4 + 1) * FH];
    float w2 = Wb[(k4*4 + 2) * FH];
    float w3 = Wb[(k4*4 + 3) * FH];
    float4 h0 = *(const float4*)&inS[ah*4 + 0][k4*4];
    float4 h1 = *(const float4*)&inS[ah*4 + 1][k4*4];
    float4 h2 = *(const float4*)&inS[ah*4 + 2][k4*4];
    float4 h3 = *(const float4*)&inS[ah*4 + 3][k4*4];
    acc0 = fmaf(h0.x, w0, acc0); acc1 = fmaf(h1.x, w0, acc1);
    acc2 = fmaf(h2.x, w0, acc2); acc3 = fmaf(h3.x, w0, acc3);
    acc0 = fmaf(h0.y, w1, acc0); acc1 = fmaf(h1.y, w1, acc1);
    acc2 = fmaf(h2.y, w1, acc2); acc3 = fmaf(h3.y, w1, acc3);
    acc0 = fmaf(h0.z, w2, acc0); acc1 = fmaf(h1.z, w2, acc1);
    acc2 = fmaf(h2.z, w2, acc2); acc3 = fmaf(h3.z, w2, acc3);
    acc0 = fmaf(h0.w, w3, acc0); acc1 = fmaf(h1.w, w3, acc1);
    acc2 = fmaf(h2.w, w3, acc2); acc3 = fmaf(h3.w, w3, acc3);
  }
  float* Ob = O + (size_t)(a0 + ah*4) * 640 + fam * 128 + f1;
  Ob[0]    = acc0;
  Ob[640]  = acc1;
  Ob[1280] = acc2;
  Ob[1920] = acc3;
}

// Node 3: balanced MLP over the compacted queue — block bt handles survivors
// [bt*4, bt*4+4); 335 of 512 blocks do exactly one iteration.
__global__ __launch_bounds__(256) void mlp_kernel(
    const Rec* __restrict__ recs, const unsigned* __restrict__ gcnt,
    const float* __restrict__ O,
    const float* __restrict__ W1, const float* __restrict__ b1,
    const float* __restrict__ W2, const float* __restrict__ b2,
    const float* __restrict__ W3, const float* __restrict__ b3,
    float* __restrict__ out) {
  __shared__ float epS[NE][DRBF];
  __shared__ float h2S[NE][FH];
  __shared__ float part2[4][NE][64];
  __shared__ float rS[NE][3];
  __shared__ unsigned aS[NE];
  __shared__ float cwS[NE];
  __shared__ unsigned pS[NE];

  const int t    = threadIdx.x;
  const int lane = t & 63;
  const int wave = t >> 6;
  int n = (int)*gcnt; if (n > RECMAX) n = RECMAX;
  if ((int)blockIdx.x * NE >= n) return;

  const int f1 = t & 127;
  const int eh = t >> 7;
  const float b1v = b1[f1];
  const float b2v = b2[lane];
  const float w3v = W3[lane];
  const float b3v = b3[0];

  for (int bt = blockIdx.x; bt * NE < n; bt += gridDim.x) {
    {
      const int s = bt * NE + wave;
      Rec r;
      if (s < n) r = recs[s];
      else { r.dx = 1.f; r.dy = 0.f; r.dz = 0.f; r.ap = 0xFFFFFFFFu; }
      float d = sqrtf(r.dx*r.dx + r.dy*r.dy + r.dz*r.dz);
      float inv = 1.0f / (d + 1e-8f);
      if (lane < DRBF) epS[wave][lane] = sinf(d * (float)(lane+1) * (PI_F/CUT)) / d;
      if (lane == 0) {
        rS[wave][0] = r.dx*inv; rS[wave][1] = r.dy*inv; rS[wave][2] = r.dz*inv;
        aS[wave] = (r.ap == 0xFFFFFFFFu) ? 0u : (r.ap >> 16);
        cwS[wave] = 0.5f * (cosf((PI_F/CUT) * d) + 1.0f);
        pS[wave]  = (r.ap == 0xFFFFFFFFu) ? 0xFFFFFFFFu : (r.ap & 0xFFFFu);
      }
    }
    __syncthreads();

    // L1: thread (f1, eh) -> z for edges eh*2, eh*2+1
    {
      const int e0 = eh*2, e1 = eh*2 + 1;
      const float* Oa  = O + (size_t)aS[e0] * 640 + f1;
      const float* Obp = O + (size_t)aS[e1] * 640 + f1;
      float o00 = Oa[0],  o01 = Oa[128],  o02 = Oa[256],  o03 = Oa[384],  o04 = Oa[512];
      float o10 = Obp[0], o11 = Obp[128], o12 = Obp[256], o13 = Obp[384], o14 = Obp[512];
      float z0 = b1v + o03 + o04 + rS[e0][0]*o00 + rS[e0][1]*o01 + rS[e0][2]*o02;
      float z1 = b1v + o13 + o14 + rS[e1][0]*o10 + rS[e1][1]*o11 + rS[e1][2]*o12;
      const float* Wb = W1 + f1;          // RBF rows 0..31
      #pragma unroll
      for (int k = 0; k < DRBF; ++k) {
        float w = Wb[k * FH];
        z0 = fmaf(epS[e0][k], w, z0);
        z1 = fmaf(epS[e1][k], w, z1);
      }
      h2S[e0][f1] = z0 / (1.0f + __expf(-z0));
      h2S[e1][f1] = z1 / (1.0f + __expf(-z1));
    }
    __syncthreads();

    // L2 (k-split): wave = k-quarter, lane = out-feature
    {
      float a0 = 0.f, a1 = 0.f, a2 = 0.f, a3 = 0.f;
      const float* Wq = W2 + (wave * 32) * 64 + lane;
      const float* h0p = &h2S[0][wave * 32];
      const float* h1p = &h2S[1][wave * 32];
      const float* h2p = &h2S[2][wave * 32];
      const float* h3p = &h2S[3][wave * 32];
      #pragma unroll
      for (int k4 = 0; k4 < 8; ++k4) {
        float w0 = Wq[(k4*4 + 0) * 64];
        float w1 = Wq[(k4*4 + 1) * 64];
        float w2 = Wq[(k4*4 + 2) * 64];
        float w3 = Wq[(k4*4 + 3) * 64];
        float4 h0 = *(const float4*)&h0p[k4*4];
        float4 h1 = *(const float4*)&h1p[k4*4];
        float4 h2 = *(const float4*)&h2p[k4*4];
        float4 h3 = *(const float4*)&h3p[k4*4];
        a0 = fmaf(h0.x, w0, a0); a1 = fmaf(h1.x, w0, a1);
        a2 = fmaf(h2.x, w0, a2); a3 = fmaf(h3.x, w0, a3);
        a0 = fmaf(h0.y, w1, a0); a1 = fmaf(h1.y, w1, a1);
        a2 = fmaf(h2.y, w1, a2); a3 = fmaf(h3.y, w1, a3);
        a0 = fmaf(h0.z, w2, a0); a1 = fmaf(h1.z, w2, a1);
        a2 = fmaf(h2.z, w2, a2); a3 = fmaf(h3.z, w2, a3);
        a0 = fmaf(h0.w, w3, a0); a1 = fmaf(h1.w, w3, a1);
        a2 = fmaf(h2.w, w3, a2); a3 = fmaf(h3.w, w3, a3);
      }
      part2[wave][0][lane] = a0;
      part2[wave][1][lane] = a1;
      part2[wave][2][lane] = a2;
      part2[wave][3][lane] = a3;
    }
    __syncthreads();

    // finish: wave = edge, lane = out-feature; silu + W3-dot + scatter
    {
      float z = part2[0][wave][lane] + part2[1][wave][lane]
              + part2[2][wave][lane] + part2[3][wave][lane] + b2v;
      float h2 = z / (1.0f + __expf(-z));
      float rs = h2 * w3v;
      #pragma unroll
      for (int off = 32; off; off >>= 1) rs += __shfl_xor(rs, off, 64);
      if (lane == 0) {
        unsigned p = pS[wave];
        if (p != 0xFFFFFFFFu) atomicAdd(&out[p], (rs + b3v) * cwS[wave]);
      }
    }
    __syncthreads();
  }
}

extern "C" void kernel_launch(void* const* d_in, const int* in_sizes, int n_in,
                              void* d_out, int out_size, void* d_ws, size_t ws_size,
                              hipStream_t stream) {
  const float* S         = (const float*)d_in[0];
  const float* V         = (const float*)d_in[1];
  const float* atom_xyz  = (const float*)d_in[2];
  const float* probe_xyz = (const float*)d_in[3];
  const float* cell      = (const float*)d_in[4];
  const float* pdisp     = (const float*)d_in[5];
  const float* W1        = (const float*)d_in[6];
  const float* b1        = (const float*)d_in[7];
  const float* W2        = (const float*)d_in[8];
  const float* b2        = (const float*)d_in[9];
  const float* W3        = (const float*)d_in[10];
  const float* b3        = (const float*)d_in[11];
  const int*   pe        = (const int*)d_in[12];
  float* out = (float*)d_out;

  unsigned* gcnt = (unsigned*)d_ws;
  Rec*      recs = (Rec*)((char*)d_ws + 256);
  float*    O    = (float*)((char*)d_ws + (1u << 20));   // 2048 x 640 floats

  hipMemsetAsync(d_ws, 0, 16, stream);
  combined_kernel<<<ABLK + FBLK, 256, 0, stream>>>(pe, pdisp, cell, atom_xyz,
                                                   probe_xyz, S, V, W1,
                                                   gcnt, recs, O, out);
  mlp_kernel<<<512, 256, 0, stream>>>(recs, gcnt, O, W1, b1, W2, b2, W3, b3, out);
}

// Round 16
// 27.845 us; speedup vs baseline: 4.9836x; 1.2014x over previous
//
#include <hip/hip_runtime.h>
#include <math.h>

#define BB 4
#define NN 512
#define PP 2048
#define EE 32768
#define FH 128
#define DRBF 32
#define CUT 4.0f
#define PI_F 3.14159265358979323846f
#define NE 4
#define CHUNK 64          // raw edges per fused block -> 2048 blocks = 8/CU
#define AT2 16            // atoms per atom_kernel block -> 640 blocks

// ws layout: O at ws+256: [2048 atoms][640] floats = 5.24 MB
//   O[a][  0..127]=M0  [128..255]=M1  [256..383]=M2 = V[a]@W1_q (rows 32..159)
//   O[a][384..511]=Cn = n_e@W1_n (rows 160..287)
//   O[a][512..639]=Cs = S@W1_s  (rows 288..415)

// Node 1: per-atom precompute + zero `out` (blocks 0-7). Each weight load
// feeds 8 atoms (AT2=16 halves W1 L2 traffic vs R12).
__global__ __launch_bounds__(256) void atom_kernel(
    const float* __restrict__ S, const float* __restrict__ V,
    const float* __restrict__ W1, float* __restrict__ O,
    float* __restrict__ out) {
  __shared__ float inS[AT2][128];   // 8 KB
  const int t = threadIdx.x;
  if (blockIdx.x < 8)
    ((float4*)out)[blockIdx.x * 256 + t] = make_float4(0.f, 0.f, 0.f, 0.f);

  const int fam = blockIdx.x % 5;
  const int a0  = (blockIdx.x / 5) * AT2;

  // stage the needed 128-vector for 16 atoms: 512 float4, 2/thread
  #pragma unroll
  for (int i = 0; i < 2; ++i) {
    int idx = t + i * 256;
    int a  = idx >> 5;          // 0..15
    int k4 = idx & 31;          // float4 index
    float4 v;
    if (fam < 3) {
      v = *(const float4*)&V[(size_t)(a0 + a) * 384 + fam * 128 + k4 * 4];
    } else if (fam == 4) {
      v = *(const float4*)&S[(size_t)(a0 + a) * 128 + k4 * 4];
    } else { // fam == 3: n_e from V
      float4 x = *(const float4*)&V[(size_t)(a0 + a) * 384 +   0 + k4 * 4];
      float4 y = *(const float4*)&V[(size_t)(a0 + a) * 384 + 128 + k4 * 4];
      float4 z = *(const float4*)&V[(size_t)(a0 + a) * 384 + 256 + k4 * 4];
      v.x = sqrtf(x.x*x.x + y.x*y.x + z.x*z.x);
      v.y = sqrtf(x.y*x.y + y.y*y.y + z.y*z.y);
      v.z = sqrtf(x.z*x.z + y.z*y.z + z.z*z.z);
      v.w = sqrtf(x.w*x.w + y.w*y.w + z.w*z.w);
    }
    *(float4*)&inS[a][k4 * 4] = v;
  }
  __syncthreads();

  const int f1 = t & 127;
  const int ah = t >> 7;     // atoms ah*8 .. ah*8+7
  const int wrow = (fam < 3) ? 32 : ((fam == 3) ? 160 : 288);
  const float* Wb = W1 + (size_t)wrow * FH + f1;

  float acc[8];
  #pragma unroll
  for (int j = 0; j < 8; ++j) acc[j] = 0.f;

  #pragma unroll 4
  for (int k4 = 0; k4 < 32; ++k4) {
    float w0 = Wb[(k4*4 + 0) * FH];
    float w1 = Wb[(k4*4 + 1) * FH];
    float w2 = Wb[(k4*4 + 2) * FH];
    float w3 = Wb[(k4*4 + 3) * FH];
    #pragma unroll
    for (int j = 0; j < 8; ++j) {
      float4 hv = *(const float4*)&inS[ah*8 + j][k4*4];
      acc[j] = fmaf(hv.x, w0, acc[j]);
      acc[j] = fmaf(hv.y, w1, acc[j]);
      acc[j] = fmaf(hv.z, w2, acc[j]);
      acc[j] = fmaf(hv.w, w3, acc[j]);
    }
  }
  #pragma unroll
  for (int j = 0; j < 8; ++j)
    O[(size_t)(a0 + ah*8 + j) * 640 + fam * 128 + f1] = acc[j];
}

// Node 2: fused filter + per-edge MLP. 2048 blocks x 64-edge chunks (8/CU):
// 48% of blocks exit after filter; the rest do exactly one MLP iteration.
__global__ __launch_bounds__(256) void fused_kernel(
    const int* __restrict__ pe, const float* __restrict__ pdisp,
    const float* __restrict__ cell, const float* __restrict__ atom_xyz,
    const float* __restrict__ probe_xyz,
    const float* __restrict__ O,
    const float* __restrict__ W1, const float* __restrict__ b1,
    const float* __restrict__ W2, const float* __restrict__ b2,
    const float* __restrict__ W3, const float* __restrict__ b3,
    float* __restrict__ out) {
  __shared__ float sdx[CHUNK], sdy[CHUNK], sdz[CHUNK];
  __shared__ unsigned sap[CHUNK];
  __shared__ int mcnt;
  __shared__ float epS[NE][DRBF];
  __shared__ float h2S[NE][FH];
  __shared__ float part2[4][NE][64];
  __shared__ float rS[NE][3];
  __shared__ unsigned aS[NE];
  __shared__ float cwS[NE];
  __shared__ unsigned pS[NE];

  const int t    = threadIdx.x;
  const int lane = t & 63;
  const int wave = t >> 6;
  if (t == 0) mcnt = 0;
  __syncthreads();

  // ---- Phase F: filter this block's 64 edges (threads 0-63) ----
  const int b = blockIdx.x >> 9;            // 512 blocks per batch
  if (t < CHUNK) {
    const int e = blockIdx.x * CHUNK + t;
    const float* cb = cell + b * 9;
    int2 ap = ((const int2*)pe)[e];
    float pd0 = pdisp[e*3], pd1 = pdisp[e*3+1], pd2 = pdisp[e*3+2];
    float d0 = pd0*cb[0] + pd1*cb[3] + pd2*cb[6];
    float d1 = pd0*cb[1] + pd1*cb[4] + pd2*cb[7];
    float d2 = pd0*cb[2] + pd1*cb[5] + pd2*cb[8];
    int ag = b*NN + ap.x;
    int pg = b*PP + ap.y;
    float dx = probe_xyz[pg*3]   - (atom_xyz[ag*3]   + d0);
    float dy = probe_xyz[pg*3+1] - (atom_xyz[ag*3+1] + d1);
    float dz = probe_xyz[pg*3+2] - (atom_xyz[ag*3+2] + d2);
    float dist2 = dx*dx + dy*dy + dz*dz;
    if (dist2 < CUT*CUT) {
      int s = atomicAdd(&mcnt, 1);   // LDS atomic
      sdx[s] = dx; sdy[s] = dy; sdz[s] = dz;
      sap[s] = ((unsigned)ag << 16) | (unsigned)pg;
    }
  }
  __syncthreads();
  const int m = mcnt;
  if (m == 0) return;

  const int f1 = t & 127;
  const int eh = t >> 7;
  const float b1v = b1[f1];
  const float b2v = b2[lane];
  const float w3v = W3[lane];
  const float b3v = b3[0];

  for (int s0 = 0; s0 < m; s0 += NE) {     // one pass for >99.9% of blocks
    {
      const int s = s0 + wave;
      float dx, dy, dz; unsigned ap_;
      if (s < m) { dx = sdx[s]; dy = sdy[s]; dz = sdz[s]; ap_ = sap[s]; }
      else       { dx = 1.f; dy = 0.f; dz = 0.f; ap_ = 0xFFFFFFFFu; }
      float d = sqrtf(dx*dx + dy*dy + dz*dz);
      float inv = 1.0f / (d + 1e-8f);
      if (lane < DRBF) epS[wave][lane] = sinf(d * (float)(lane+1) * (PI_F/CUT)) / d;
      if (lane == 0) {
        rS[wave][0] = dx*inv; rS[wave][1] = dy*inv; rS[wave][2] = dz*inv;
        aS[wave] = (ap_ == 0xFFFFFFFFu) ? 0u : (ap_ >> 16);
        cwS[wave] = 0.5f * (cosf((PI_F/CUT) * d) + 1.0f);
        pS[wave]  = (ap_ == 0xFFFFFFFFu) ? 0xFFFFFFFFu : (ap_ & 0xFFFFu);
      }
    }
    __syncthreads();

    // L1: thread (f1, eh) -> z for edges eh*2, eh*2+1
    {
      const int e0 = eh*2, e1 = eh*2 + 1;
      const float* Oa  = O + (size_t)aS[e0] * 640 + f1;
      const float* Obp = O + (size_t)aS[e1] * 640 + f1;
      float o00 = Oa[0],  o01 = Oa[128],  o02 = Oa[256],  o03 = Oa[384],  o04 = Oa[512];
      float o10 = Obp[0], o11 = Obp[128], o12 = Obp[256], o13 = Obp[384], o14 = Obp[512];
      float z0 = b1v + o03 + o04 + rS[e0][0]*o00 + rS[e0][1]*o01 + rS[e0][2]*o02;
      float z1 = b1v + o13 + o14 + rS[e1][0]*o10 + rS[e1][1]*o11 + rS[e1][2]*o12;
      const float* Wb = W1 + f1;          // RBF rows 0..31
      #pragma unroll
      for (int k = 0; k < DRBF; ++k) {
        float w = Wb[k * FH];
        z0 = fmaf(epS[e0][k], w, z0);
        z1 = fmaf(epS[e1][k], w, z1);
      }
      h2S[e0][f1] = z0 / (1.0f + __expf(-z0));
      h2S[e1][f1] = z1 / (1.0f + __expf(-z1));
    }
    __syncthreads();

    // L2 (k-split): wave = k-quarter, lane = out-feature
    {
      float a0 = 0.f, a1 = 0.f, a2 = 0.f, a3 = 0.f;
      const float* Wq = W2 + (wave * 32) * 64 + lane;
      const float* h0p = &h2S[0][wave * 32];
      const float* h1p = &h2S[1][wave * 32];
      const float* h2p = &h2S[2][wave * 32];
      const float* h3p = &h2S[3][wave * 32];
      #pragma unroll
      for (int k4 = 0; k4 < 8; ++k4) {
        float w0 = Wq[(k4*4 + 0) * 64];
        float w1 = Wq[(k4*4 + 1) * 64];
        float w2 = Wq[(k4*4 + 2) * 64];
        float w3 = Wq[(k4*4 + 3) * 64];
        float4 h0 = *(const float4*)&h0p[k4*4];
        float4 h1 = *(const float4*)&h1p[k4*4];
        float4 h2 = *(const float4*)&h2p[k4*4];
        float4 h3 = *(const float4*)&h3p[k4*4];
        a0 = fmaf(h0.x, w0, a0); a1 = fmaf(h1.x, w0, a1);
        a2 = fmaf(h2.x, w0, a2); a3 = fmaf(h3.x, w0, a3);
        a0 = fmaf(h0.y, w1, a0); a1 = fmaf(h1.y, w1, a1);
        a2 = fmaf(h2.y, w1, a2); a3 = fmaf(h3.y, w1, a3);
        a0 = fmaf(h0.z, w2, a0); a1 = fmaf(h1.z, w2, a1);
        a2 = fmaf(h2.z, w2, a2); a3 = fmaf(h3.z, w2, a3);
        a0 = fmaf(h0.w, w3, a0); a1 = fmaf(h1.w, w3, a1);
        a2 = fmaf(h2.w, w3, a2); a3 = fmaf(h3.w, w3, a3);
      }
      part2[wave][0][lane] = a0;
      part2[wave][1][lane] = a1;
      part2[wave][2][lane] = a2;
      part2[wave][3][lane] = a3;
    }
    __syncthreads();

    // finish: wave = edge, lane = out-feature; silu + W3-dot + scatter
    {
      float z = part2[0][wave][lane] + part2[1][wave][lane]
              + part2[2][wave][lane] + part2[3][wave][lane] + b2v;
      float h2 = z / (1.0f + __expf(-z));
      float rs = h2 * w3v;
      #pragma unroll
      for (int off = 32; off; off >>= 1) rs += __shfl_xor(rs, off, 64);
      if (lane == 0) {
        unsigned p = pS[wave];
        if (p != 0xFFFFFFFFu) atomicAdd(&out[p], (rs + b3v) * cwS[wave]);
      }
    }
    __syncthreads();
  }
}

extern "C" void kernel_launch(void* const* d_in, const int* in_sizes, int n_in,
                              void* d_out, int out_size, void* d_ws, size_t ws_size,
                              hipStream_t stream) {
  const float* S         = (const float*)d_in[0];
  const float* V         = (const float*)d_in[1];
  const float* atom_xyz  = (const float*)d_in[2];
  const float* probe_xyz = (const float*)d_in[3];
  const float* cell      = (const float*)d_in[4];
  const float* pdisp     = (const float*)d_in[5];
  const float* W1        = (const float*)d_in[6];
  const float* b1        = (const float*)d_in[7];
  const float* W2        = (const float*)d_in[8];
  const float* b2        = (const float*)d_in[9];
  const float* W3        = (const float*)d_in[10];
  const float* b3        = (const float*)d_in[11];
  const int*   pe        = (const int*)d_in[12];
  float* out = (float*)d_out;

  float* O = (float*)((char*)d_ws + 256);   // 2048 x 640 floats

  atom_kernel<<<(BB*NN/AT2)*5, 256, 0, stream>>>(S, V, W1, O, out);
  fused_kernel<<<BB*EE/CHUNK, 256, 0, stream>>>(pe, pdisp, cell, atom_xyz, probe_xyz,
                                                O, W1, b1, W2, b2, W3, b3, out);
}

// Round 17
// 24.723 us; speedup vs baseline: 5.6129x; 1.1263x over previous
//
#include <hip/hip_runtime.h>
#include <math.h>

#define BB 4
#define NN 512
#define PP 2048
#define EE 32768
#define FH 128
#define DRBF 32
#define CUT 4.0f
#define PI_F 3.14159265358979323846f
#define CHUNK 128         // raw edges per fused block -> 1024 blocks = 4/CU
#define AT2 8             // atoms per atom_kernel block (R12-proven)

// ws layout: O at ws+256: [2048 atoms][640] floats = 5.24 MB
//   O[a][  0..127]=M0  [128..255]=M1  [256..383]=M2 = V[a]@W1_q (rows 32..159)
//   O[a][384..511]=Cn = n_e@W1_n (rows 160..287)
//   O[a][512..639]=Cs = S@W1_s  (rows 288..415)

// Node 1: per-atom precompute (R12-proven, zero-spill) + zero `out` (blocks 0-7).
__global__ __launch_bounds__(256) void atom_kernel(
    const float* __restrict__ S, const float* __restrict__ V,
    const float* __restrict__ W1, float* __restrict__ O,
    float* __restrict__ out) {
  __shared__ float inS[AT2][128];   // 4 KB
  const int t = threadIdx.x;
  if (blockIdx.x < 8)
    ((float4*)out)[blockIdx.x * 256 + t] = make_float4(0.f, 0.f, 0.f, 0.f);

  const int fam = blockIdx.x % 5;
  const int a0  = (blockIdx.x / 5) * AT2;

  {
    int a  = t >> 5;          // 0..7
    int k4 = t & 31;          // float4 index 0..31
    float4 v;
    if (fam < 3) {
      v = *(const float4*)&V[(size_t)(a0 + a) * 384 + fam * 128 + k4 * 4];
    } else if (fam == 4) {
      v = *(const float4*)&S[(size_t)(a0 + a) * 128 + k4 * 4];
    } else { // fam == 3: n_e from V
      float4 x = *(const float4*)&V[(size_t)(a0 + a) * 384 +   0 + k4 * 4];
      float4 y = *(const float4*)&V[(size_t)(a0 + a) * 384 + 128 + k4 * 4];
      float4 z = *(const float4*)&V[(size_t)(a0 + a) * 384 + 256 + k4 * 4];
      v.x = sqrtf(x.x*x.x + y.x*y.x + z.x*z.x);
      v.y = sqrtf(x.y*x.y + y.y*y.y + z.y*z.y);
      v.z = sqrtf(x.z*x.z + y.z*y.z + z.z*z.z);
      v.w = sqrtf(x.w*x.w + y.w*y.w + z.w*z.w);
    }
    *(float4*)&inS[a][k4 * 4] = v;
  }
  __syncthreads();

  const int f1 = t & 127;
  const int ah = t >> 7;     // atoms ah*4 .. ah*4+3
  const int wrow = (fam < 3) ? 32 : ((fam == 3) ? 160 : 288);
  const float* Wb = W1 + (size_t)wrow * FH + f1;

  float acc0 = 0.f, acc1 = 0.f, acc2 = 0.f, acc3 = 0.f;
  #pragma unroll 4
  for (int k4 = 0; k4 < 32; ++k4) {
    float w0 = Wb[(k4*4 + 0) * FH];
    float w1 = Wb[(k4*4 + 1) * FH];
    float w2 = Wb[(k4*4 + 2) * FH];
    float w3 = Wb[(k4*4 + 3) * FH];
    float4 h0 = *(const float4*)&inS[ah*4 + 0][k4*4];
    float4 h1 = *(const float4*)&inS[ah*4 + 1][k4*4];
    float4 h2 = *(const float4*)&inS[ah*4 + 2][k4*4];
    float4 h3 = *(const float4*)&inS[ah*4 + 3][k4*4];
    acc0 = fmaf(h0.x, w0, acc0); acc1 = fmaf(h1.x, w0, acc1);
    acc2 = fmaf(h2.x, w0, acc2); acc3 = fmaf(h3.x, w0, acc3);
    acc0 = fmaf(h0.y, w1, acc0); acc1 = fmaf(h1.y, w1, acc1);
    acc2 = fmaf(h2.y, w1, acc2); acc3 = fmaf(h3.y, w1, acc3);
    acc0 = fmaf(h0.z, w2, acc0); acc1 = fmaf(h1.z, w2, acc1);
    acc2 = fmaf(h2.z, w2, acc2); acc3 = fmaf(h3.z, w2, acc3);
    acc0 = fmaf(h0.w, w3, acc0); acc1 = fmaf(h1.w, w3, acc1);
    acc2 = fmaf(h2.w, w3, acc2); acc3 = fmaf(h3.w, w3, acc3);
  }
  float* Ob = O + (size_t)(a0 + ah*4) * 640 + fam * 128 + f1;
  Ob[0]    = acc0;
  Ob[640]  = acc1;
  Ob[1280] = acc2;
  Ob[1920] = acc3;
}

// Node 2: fused filter + wave-per-edge MLP. One barrier total; each wave owns
// one survivor end-to-end (ep/h2 via per-wave LDS, wave-internal fences only);
// no dummy-edge work; 4096 wave-slots for ~1340 edges -> 1 pass, no tail.
__global__ __launch_bounds__(256) void fused_kernel(
    const int* __restrict__ pe, const float* __restrict__ pdisp,
    const float* __restrict__ cell, const float* __restrict__ atom_xyz,
    const float* __restrict__ probe_xyz,
    const float* __restrict__ O,
    const float* __restrict__ W1, const float* __restrict__ b1,
    const float* __restrict__ W2, const float* __restrict__ b2,
    const float* __restrict__ W3, const float* __restrict__ b3,
    float* __restrict__ out) {
  __shared__ float sdx[CHUNK], sdy[CHUNK], sdz[CHUNK];   // 1.5 KB
  __shared__ unsigned sap[CHUNK];                        // 0.5 KB
  __shared__ int mcnt;
  __shared__ float epW[4][DRBF];     // per-wave RBF vector
  __shared__ float h2W[4][FH];       // per-wave hidden vector

  const int t    = threadIdx.x;
  const int lane = t & 63;
  const int wave = t >> 6;
  if (t == 0) mcnt = 0;
  __syncthreads();

  // ---- Phase F: filter this block's 128 edges (threads 0-127) ----
  const int b = blockIdx.x >> 8;            // 256 blocks per batch
  if (t < CHUNK) {
    const int e = blockIdx.x * CHUNK + t;
    const float* cb = cell + b * 9;
    int2 ap = ((const int2*)pe)[e];
    float pd0 = pdisp[e*3], pd1 = pdisp[e*3+1], pd2 = pdisp[e*3+2];
    float d0 = pd0*cb[0] + pd1*cb[3] + pd2*cb[6];
    float d1 = pd0*cb[1] + pd1*cb[4] + pd2*cb[7];
    float d2 = pd0*cb[2] + pd1*cb[5] + pd2*cb[8];
    int ag = b*NN + ap.x;
    int pg = b*PP + ap.y;
    float dx = probe_xyz[pg*3]   - (atom_xyz[ag*3]   + d0);
    float dy = probe_xyz[pg*3+1] - (atom_xyz[ag*3+1] + d1);
    float dz = probe_xyz[pg*3+2] - (atom_xyz[ag*3+2] + d2);
    float dist2 = dx*dx + dy*dy + dz*dz;
    if (dist2 < CUT*CUT) {
      int s = atomicAdd(&mcnt, 1);   // LDS atomic
      sdx[s] = dx; sdy[s] = dy; sdz[s] = dz;
      sap[s] = ((unsigned)ag << 16) | (unsigned)pg;
    }
  }
  __syncthreads();                   // the only block-wide barrier
  const int m = mcnt;
  if (m == 0) return;

  // loop-invariant params (per lane)
  const float b1a = b1[lane];
  const float b1b = b1[lane + 64];
  const float b2v = b2[lane];
  const float w3v = W3[lane];
  const float b3v = b3[0];

  // ---- wave-per-edge MLP: wave handles survivors wave, wave+4, ... ----
  for (int s = wave; s < m; s += 4) {
    float dx = sdx[s], dy = sdy[s], dz = sdz[s];   // LDS broadcast
    unsigned ap_ = sap[s];
    unsigned a = ap_ >> 16;
    unsigned p = ap_ & 0xFFFFu;
    float d = sqrtf(dx*dx + dy*dy + dz*dz);
    float inv = 1.0f / (d + 1e-8f);
    float rh0 = dx*inv, rh1 = dy*inv, rh2 = dz*inv;
    float cw = 0.5f * (cosf((PI_F/CUT) * d) + 1.0f);
    if (lane < DRBF) epW[wave][lane] = sinf(d * (float)(lane+1) * (PI_F/CUT)) / d;
    __threadfence_block();           // wave-internal LDS write->read visibility

    // ---- L1: lane computes features lane and lane+64 ----
    const float* Oa = O + (size_t)a * 640;
    float o0a = Oa[lane],       o1a = Oa[128+lane], o2a = Oa[256+lane];
    float o3a = Oa[384+lane],   o4a = Oa[512+lane];
    float o0b = Oa[64+lane],    o1b = Oa[192+lane], o2b = Oa[320+lane];
    float o3b = Oa[448+lane],   o4b = Oa[576+lane];
    float za = b1a + o3a + o4a + rh0*o0a + rh1*o1a + rh2*o2a;
    float zb = b1b + o3b + o4b + rh0*o0b + rh1*o1b + rh2*o2b;
    #pragma unroll 1
    for (int g = 0; g < 2; ++g) {    // 2 groups of 16 k -> <=32 loads in flight
      const int k0 = g * 16;
      #pragma unroll
      for (int k = 0; k < 16; ++k) {
        float wa = W1[(k0 + k) * FH + lane];
        float wb = W1[(k0 + k) * FH + lane + 64];
        float e  = epW[wave][k0 + k];
        za = fmaf(e, wa, za);
        zb = fmaf(e, wb, zb);
      }
    }
    float ha = za / (1.0f + __expf(-za));
    float hb = zb / (1.0f + __expf(-zb));
    h2W[wave][lane]      = ha;
    h2W[wave][lane + 64] = hb;
    __threadfence_block();

    // ---- L2: lane = out-feature; 4 groups of 32 k ----
    float acc = b2v;
    #pragma unroll 1
    for (int g = 0; g < 4; ++g) {
      const int k0 = g * 32;
      #pragma unroll
      for (int k = 0; k < 32; ++k) {
        acc = fmaf(h2W[wave][k0 + k], W2[(k0 + k) * 64 + lane], acc);
      }
    }
    float h2 = acc / (1.0f + __expf(-acc));

    // ---- L3: dot with W3 across 64 lanes, one atomic ----
    float rs = h2 * w3v;
    #pragma unroll
    for (int off = 32; off; off >>= 1) rs += __shfl_xor(rs, off, 64);
    if (lane == 0) atomicAdd(&out[p], (rs + b3v) * cw);

    __threadfence_block();           // epW/h2W safe to overwrite next s
  }
}

extern "C" void kernel_launch(void* const* d_in, const int* in_sizes, int n_in,
                              void* d_out, int out_size, void* d_ws, size_t ws_size,
                              hipStream_t stream) {
  const float* S         = (const float*)d_in[0];
  const float* V         = (const float*)d_in[1];
  const float* atom_xyz  = (const float*)d_in[2];
  const float* probe_xyz = (const float*)d_in[3];
  const float* cell      = (const float*)d_in[4];
  const float* pdisp     = (const float*)d_in[5];
  const float* W1        = (const float*)d_in[6];
  const float* b1        = (const float*)d_in[7];
  const float* W2        = (const float*)d_in[8];
  const float* b2        = (const float*)d_in[9];
  const float* W3        = (const float*)d_in[10];
  const float* b3        = (const float*)d_in[11];
  const int*   pe        = (const int*)d_in[12];
  float* out = (float*)d_out;

  float* O = (float*)((char*)d_ws + 256);   // 2048 x 640 floats

  atom_kernel<<<(BB*NN/AT2)*5, 256, 0, stream>>>(S, V, W1, O, out);
  fused_kernel<<<BB*EE/CHUNK, 256, 0, stream>>>(pe, pdisp, cell, atom_xyz, probe_xyz,
                                                O, W1, b1, W2, b2, W3, b3, out);
}

// Round 18
// 19.748 us; speedup vs baseline: 7.0271x; 1.2519x over previous
//
#include <hip/hip_runtime.h>
#include <math.h>

#define BB 4
#define NN 512
#define PP 2048
#define EE 32768
#define FH 128
#define DRBF 32
#define CUT 4.0f
#define PI_F 3.14159265358979323846f
#define NE 4
#define CHUNK 256         // raw edges per fused block (R12-proven)
#define AT2 8             // atoms per atom_kernel block

// ws layout: O at ws+256: [2048 atoms][640] floats = 5.24 MB
//   O[a][  0..127]=M0  [128..255]=M1  [256..383]=M2 = V[a]@W1_q (rows 32..159)
//   O[a][384..511]=Cn = n_e@W1_n (rows 160..287)
//   O[a][512..639]=Cs = S@W1_s  (rows 288..415)

// Node 1: per-atom precompute + zero `out` (blocks 0-7).
// k-split register tile: thread = (kh in 8 k-slices) x (fg in 32 feat-quads);
// per thread 16k x 8 atoms x 4 feats. LDS b128 count: 32/thread (4x fewer than
// R12 -> removes the ~12.8us LDS-issue serialization); W1 read once per block.
__global__ __launch_bounds__(256) void atom_kernel(
    const float* __restrict__ S, const float* __restrict__ V,
    const float* __restrict__ W1, float* __restrict__ O,
    float* __restrict__ out) {
  __shared__ float inS[AT2][128];       // 4 KB
  __shared__ float red[8][AT2][128];    // 32 KB [kh][atom][feat]
  const int t = threadIdx.x;
  if (blockIdx.x < 8)
    ((float4*)out)[blockIdx.x * 256 + t] = make_float4(0.f, 0.f, 0.f, 0.f);

  const int fam = blockIdx.x % 5;
  const int a0  = (blockIdx.x / 5) * AT2;

  // stage the needed 128-vector per atom (256 float4, 1/thread)
  {
    int a  = t >> 5;          // 0..7
    int k4 = t & 31;          // float4 index 0..31
    float4 v;
    if (fam < 3) {
      v = *(const float4*)&V[(size_t)(a0 + a) * 384 + fam * 128 + k4 * 4];
    } else if (fam == 4) {
      v = *(const float4*)&S[(size_t)(a0 + a) * 128 + k4 * 4];
    } else { // fam == 3: n_e from V
      float4 x = *(const float4*)&V[(size_t)(a0 + a) * 384 +   0 + k4 * 4];
      float4 y = *(const float4*)&V[(size_t)(a0 + a) * 384 + 128 + k4 * 4];
      float4 z = *(const float4*)&V[(size_t)(a0 + a) * 384 + 256 + k4 * 4];
      v.x = sqrtf(x.x*x.x + y.x*y.x + z.x*z.x);
      v.y = sqrtf(x.y*x.y + y.y*y.y + z.y*z.y);
      v.z = sqrtf(x.z*x.z + y.z*y.z + z.z*z.z);
      v.w = sqrtf(x.w*x.w + y.w*y.w + z.w*z.w);
    }
    *(float4*)&inS[a][k4 * 4] = v;
  }
  __syncthreads();

  const int kh = t >> 5;     // k-slice: k in [kh*16, kh*16+16)
  const int fg = t & 31;     // feature quad: feats fg*4 .. fg*4+3
  const int k0 = kh * 16;
  const int wrow = (fam < 3) ? 32 : ((fam == 3) ? 160 : 288);
  const float* Wb = W1 + (size_t)wrow * FH + fg * 4;

  float4 acc[AT2];
  #pragma unroll
  for (int a = 0; a < AT2; ++a) acc[a] = make_float4(0.f, 0.f, 0.f, 0.f);

  #pragma unroll 2
  for (int k4 = 0; k4 < 4; ++k4) {
    const int k = k0 + k4 * 4;
    float4 w0 = *(const float4*)&Wb[(size_t)(k + 0) * FH];
    float4 w1 = *(const float4*)&Wb[(size_t)(k + 1) * FH];
    float4 w2 = *(const float4*)&Wb[(size_t)(k + 2) * FH];
    float4 w3 = *(const float4*)&Wb[(size_t)(k + 3) * FH];
    #pragma unroll
    for (int a = 0; a < AT2; ++a) {
      float4 hv = *(const float4*)&inS[a][k];
      acc[a].x = fmaf(hv.x, w0.x, acc[a].x); acc[a].y = fmaf(hv.x, w0.y, acc[a].y);
      acc[a].z = fmaf(hv.x, w0.z, acc[a].z); acc[a].w = fmaf(hv.x, w0.w, acc[a].w);
      acc[a].x = fmaf(hv.y, w1.x, acc[a].x); acc[a].y = fmaf(hv.y, w1.y, acc[a].y);
      acc[a].z = fmaf(hv.y, w1.z, acc[a].z); acc[a].w = fmaf(hv.y, w1.w, acc[a].w);
      acc[a].x = fmaf(hv.z, w2.x, acc[a].x); acc[a].y = fmaf(hv.z, w2.y, acc[a].y);
      acc[a].z = fmaf(hv.z, w2.z, acc[a].z); acc[a].w = fmaf(hv.z, w2.w, acc[a].w);
      acc[a].x = fmaf(hv.w, w3.x, acc[a].x); acc[a].y = fmaf(hv.w, w3.y, acc[a].y);
      acc[a].z = fmaf(hv.w, w3.z, acc[a].z); acc[a].w = fmaf(hv.w, w3.w, acc[a].w);
    }
  }

  // kh-partial reduction through LDS (contiguous float4, conflict-free)
  #pragma unroll
  for (int a = 0; a < AT2; ++a)
    *(float4*)&red[kh][a][fg * 4] = acc[a];
  __syncthreads();
  {
    const int a  = t >> 5;
    const int fq = t & 31;
    float4 s = make_float4(0.f, 0.f, 0.f, 0.f);
    #pragma unroll
    for (int k2 = 0; k2 < 8; ++k2) {
      float4 v = *(const float4*)&red[k2][a][fq * 4];
      s.x += v.x; s.y += v.y; s.z += v.z; s.w += v.w;
    }
    *(float4*)&O[(size_t)(a0 + a) * 640 + fam * 128 + fq * 4] = s;
  }
}

// Node 2: fused filter + per-edge MLP (verbatim R12 structure, 22.3us champion).
__global__ __launch_bounds__(256) void fused_kernel(
    const int* __restrict__ pe, const float* __restrict__ pdisp,
    const float* __restrict__ cell, const float* __restrict__ atom_xyz,
    const float* __restrict__ probe_xyz,
    const float* __restrict__ O,
    const float* __restrict__ W1, const float* __restrict__ b1,
    const float* __restrict__ W2, const float* __restrict__ b2,
    const float* __restrict__ W3, const float* __restrict__ b3,
    float* __restrict__ out) {
  __shared__ float sdx[CHUNK], sdy[CHUNK], sdz[CHUNK];
  __shared__ unsigned sap[CHUNK];
  __shared__ int mcnt;
  __shared__ float epS[NE][DRBF];
  __shared__ float h2S[NE][FH];
  __shared__ float part2[4][NE][64];
  __shared__ float rS[NE][3];
  __shared__ unsigned aS[NE];
  __shared__ float cwS[NE];
  __shared__ unsigned pS[NE];

  const int t    = threadIdx.x;
  const int lane = t & 63;
  const int wave = t >> 6;
  if (t == 0) mcnt = 0;
  __syncthreads();

  // ---- Phase F: filter this block's 256 edges (1/thread) ----
  const int e = blockIdx.x * CHUNK + t;
  const int b = blockIdx.x >> 7;          // 128 blocks per batch
  const float* cb = cell + b * 9;
  {
    int2 ap = ((const int2*)pe)[e];
    float pd0 = pdisp[e*3], pd1 = pdisp[e*3+1], pd2 = pdisp[e*3+2];
    float d0 = pd0*cb[0] + pd1*cb[3] + pd2*cb[6];
    float d1 = pd0*cb[1] + pd1*cb[4] + pd2*cb[7];
    float d2 = pd0*cb[2] + pd1*cb[5] + pd2*cb[8];
    int ag = b*NN + ap.x;
    int pg = b*PP + ap.y;
    float dx = probe_xyz[pg*3]   - (atom_xyz[ag*3]   + d0);
    float dy = probe_xyz[pg*3+1] - (atom_xyz[ag*3+1] + d1);
    float dz = probe_xyz[pg*3+2] - (atom_xyz[ag*3+2] + d2);
    float dist2 = dx*dx + dy*dy + dz*dz;
    if (dist2 < CUT*CUT) {
      int s = atomicAdd(&mcnt, 1);   // LDS atomic
      sdx[s] = dx; sdy[s] = dy; sdz[s] = dz;
      sap[s] = ((unsigned)ag << 16) | (unsigned)pg;
    }
  }
  __syncthreads();
  const int m = mcnt;
  if (m == 0) return;

  const int f1 = t & 127;     // L1 feature
  const int eh = t >> 7;      // L1 edge-half
  const float b1v = b1[f1];
  const float b2v = b2[lane];
  const float w3v = W3[lane];
  const float b3v = b3[0];

  for (int s0 = 0; s0 < m; s0 += NE) {
    {
      const int s = s0 + wave;
      float dx, dy, dz; unsigned ap_;
      if (s < m) { dx = sdx[s]; dy = sdy[s]; dz = sdz[s]; ap_ = sap[s]; }
      else       { dx = 1.f; dy = 0.f; dz = 0.f; ap_ = 0xFFFFFFFFu; }
      float d = sqrtf(dx*dx + dy*dy + dz*dz);
      float inv = 1.0f / (d + 1e-8f);
      if (lane < DRBF) epS[wave][lane] = sinf(d * (float)(lane+1) * (PI_F/CUT)) / d;
      if (lane == 0) {
        rS[wave][0] = dx*inv; rS[wave][1] = dy*inv; rS[wave][2] = dz*inv;
        aS[wave] = (ap_ == 0xFFFFFFFFu) ? 0u : (ap_ >> 16);
        cwS[wave] = 0.5f * (cosf((PI_F/CUT) * d) + 1.0f);
        pS[wave]  = (ap_ == 0xFFFFFFFFu) ? 0xFFFFFFFFu : (ap_ & 0xFFFFu);
      }
    }
    __syncthreads();

    // L1: thread (f1, eh) -> z for edges eh*2, eh*2+1
    {
      const int e0 = eh*2, e1 = eh*2 + 1;
      const float* Oa  = O + (size_t)aS[e0] * 640 + f1;
      const float* Obp = O + (size_t)aS[e1] * 640 + f1;
      float o00 = Oa[0],  o01 = Oa[128],  o02 = Oa[256],  o03 = Oa[384],  o04 = Oa[512];
      float o10 = Obp[0], o11 = Obp[128], o12 = Obp[256], o13 = Obp[384], o14 = Obp[512];
      float z0 = b1v + o03 + o04 + rS[e0][0]*o00 + rS[e0][1]*o01 + rS[e0][2]*o02;
      float z1 = b1v + o13 + o14 + rS[e1][0]*o10 + rS[e1][1]*o11 + rS[e1][2]*o12;
      const float* Wb = W1 + f1;          // RBF rows 0..31
      #pragma unroll
      for (int k = 0; k < DRBF; ++k) {
        float w = Wb[k * FH];
        z0 = fmaf(epS[e0][k], w, z0);
        z1 = fmaf(epS[e1][k], w, z1);
      }
      h2S[e0][f1] = z0 / (1.0f + __expf(-z0));
      h2S[e1][f1] = z1 / (1.0f + __expf(-z1));
    }
    __syncthreads();

    // L2 (k-split): wave = k-quarter, lane = out-feature
    {
      float a0 = 0.f, a1 = 0.f, a2 = 0.f, a3 = 0.f;
      const float* Wq = W2 + (wave * 32) * 64 + lane;
      const float* h0p = &h2S[0][wave * 32];
      const float* h1p = &h2S[1][wave * 32];
      const float* h2p = &h2S[2][wave * 32];
      const float* h3p = &h2S[3][wave * 32];
      #pragma unroll
      for (int k4 = 0; k4 < 8; ++k4) {
        float w0 = Wq[(k4*4 + 0) * 64];
        float w1 = Wq[(k4*4 + 1) * 64];
        float w2 = Wq[(k4*4 + 2) * 64];
        float w3 = Wq[(k4*4 + 3) * 64];
        float4 h0 = *(const float4*)&h0p[k4*4];
        float4 h1 = *(const float4*)&h1p[k4*4];
        float4 h2 = *(const float4*)&h2p[k4*4];
        float4 h3 = *(const float4*)&h3p[k4*4];
        a0 = fmaf(h0.x, w0, a0); a1 = fmaf(h1.x, w0, a1);
        a2 = fmaf(h2.x, w0, a2); a3 = fmaf(h3.x, w0, a3);
        a0 = fmaf(h0.y, w1, a0); a1 = fmaf(h1.y, w1, a1);
        a2 = fmaf(h2.y, w1, a2); a3 = fmaf(h3.y, w1, a3);
        a0 = fmaf(h0.z, w2, a0); a1 = fmaf(h1.z, w2, a1);
        a2 = fmaf(h2.z, w2, a2); a3 = fmaf(h3.z, w2, a3);
        a0 = fmaf(h0.w, w3, a0); a1 = fmaf(h1.w, w3, a1);
        a2 = fmaf(h2.w, w3, a2); a3 = fmaf(h3.w, w3, a3);
      }
      part2[wave][0][lane] = a0;
      part2[wave][1][lane] = a1;
      part2[wave][2][lane] = a2;
      part2[wave][3][lane] = a3;
    }
    __syncthreads();

    // finish: wave = edge, lane = out-feature; silu + W3-dot + scatter
    {
      float z = part2[0][wave][lane] + part2[1][wave][lane]
              + part2[2][wave][lane] + part2[3][wave][lane] + b2v;
      float h2 = z / (1.0f + __expf(-z));
      float rs = h2 * w3v;
      #pragma unroll
      for (int off = 32; off; off >>= 1) rs += __shfl_xor(rs, off, 64);
      if (lane == 0) {
        unsigned p = pS[wave];
        if (p != 0xFFFFFFFFu) atomicAdd(&out[p], (rs + b3v) * cwS[wave]);
      }
    }
    __syncthreads();
  }
}

extern "C" void kernel_launch(void* const* d_in, const int* in_sizes, int n_in,
                              void* d_out, int out_size, void* d_ws, size_t ws_size,
                              hipStream_t stream) {
  const float* S         = (const float*)d_in[0];
  const float* V         = (const float*)d_in[1];
  const float* atom_xyz  = (const float*)d_in[2];
  const float* probe_xyz = (const float*)d_in[3];
  const float* cell      = (const float*)d_in[4];
  const float* pdisp     = (const float*)d_in[5];
  const float* W1        = (const float*)d_in[6];
  const float* b1        = (const float*)d_in[7];
  const float* W2        = (const float*)d_in[8];
  const float* b2        = (const float*)d_in[9];
  const float* W3        = (const float*)d_in[10];
  const float* b3        = (const float*)d_in[11];
  const int*   pe        = (const int*)d_in[12];
  float* out = (float*)d_out;

  float* O = (float*)((char*)d_ws + 256);   // 2048 x 640 floats

  atom_kernel<<<(BB*NN/AT2)*5, 256, 0, stream>>>(S, V, W1, O, out);
  fused_kernel<<<BB*EE/CHUNK, 256, 0, stream>>>(pe, pdisp, cell, atom_xyz, probe_xyz,
                                                O, W1, b1, W2, b2, W3, b3, out);
}